// Round 8
// baseline (744.054 us; speedup 1.0000x reference)
//
#include <hip/hip_runtime.h>
#include <hip/hip_bf16.h>

typedef __hip_bfloat16 bf16;
typedef __attribute__((ext_vector_type(8))) short short8;
typedef __attribute__((ext_vector_type(4))) float float4v;

static __device__ __forceinline__ float b2f(bf16 x) { return __bfloat162float(x); }

// dtype-dispatched load/store: f32=1 -> buffer is float32, f32=0 -> bfloat16.
static __device__ __forceinline__ float ldf(const void* p, size_t i, int f32) {
    return f32 ? ((const float*)p)[i] : b2f(((const bf16*)p)[i]);
}
static __device__ __forceinline__ void stf(void* p, size_t i, int f32, float v) {
    if (f32) ((float*)p)[i] = v;
    else     ((bf16*)p)[i] = __float2bfloat16(v);
}
static __device__ __forceinline__ unsigned short f2bf_bits(float f) {
    bf16 h = __float2bfloat16(f);
    return *(unsigned short*)&h;
}
static __device__ __forceinline__ float bf_bits2f(unsigned short u) {
    return __uint_as_float((unsigned)u << 16);
}

// fast tanh: 1 - 2/(e^2x + 1)
static __device__ __forceinline__ float fast_tanh(float x) {
    float t = __expf(2.f * x);
    return 1.f - 2.f * __builtin_amdgcn_rcpf(t + 1.f);
}

// load 16 edge-attr channels of edge e into registers (either dtype)
static __device__ __forceinline__ void load_ea16(const void* ea, size_t e, int f32, float* er) {
    if (f32) {
        const float4* p = (const float4*)((const float*)ea + e * 16);
        #pragma unroll
        for (int q = 0; q < 4; ++q) {
            float4 v = p[q];
            er[4*q] = v.x; er[4*q+1] = v.y; er[4*q+2] = v.z; er[4*q+3] = v.w;
        }
    } else {
        const uint4* p = (const uint4*)((const bf16*)ea + e * 16);
        #pragma unroll
        for (int q = 0; q < 2; ++q) {
            uint4 u = p[q];
            er[8*q+0] = __uint_as_float(u.x << 16);
            er[8*q+1] = __uint_as_float(u.x & 0xffff0000u);
            er[8*q+2] = __uint_as_float(u.y << 16);
            er[8*q+3] = __uint_as_float(u.y & 0xffff0000u);
            er[8*q+4] = __uint_as_float(u.z << 16);
            er[8*q+5] = __uint_as_float(u.z & 0xffff0000u);
            er[8*q+6] = __uint_as_float(u.w << 16);
            er[8*q+7] = __uint_as_float(u.w & 0xffff0000u);
        }
    }
}

// ---------------- dtype detector ----------------
__global__ void detect_kernel(const unsigned short* __restrict__ a, int* __restrict__ flag)
{
    __shared__ int cnt;
    if (threadIdx.x == 0) cnt = 0;
    __syncthreads();
    unsigned e = (a[threadIdx.x] >> 7) & 0xFF;
    if (e < 100 || e > 133) atomicAdd(&cnt, 1);
    __syncthreads();
    if (threadIdx.x == 0) *flag = (cnt >= 16) ? 1 : 0;   // 1 => float32 tensors
}

// ---------------- x -> bf16 workspace copy (both node types, one launch) ----------------
__global__ __launch_bounds__(256) void convert_x_kernel(
    const void* __restrict__ xa, const void* __restrict__ xb,
    const int* __restrict__ flagp, unsigned short* __restrict__ xc, size_t n_per)
{
    const int f32 = *flagp;
    size_t i = ((size_t)blockIdx.x * 256 + threadIdx.x) * 8;
    if (i >= 2 * n_per) return;
    const void* src = (i < n_per) ? xa : xb;
    size_t o = (i < n_per) ? i : i - n_per;
    unsigned short out[8];
    if (f32) {
        const float4* p = (const float4*)((const float*)src + o);
        float4 v0 = p[0], v1 = p[1];
        out[0] = f2bf_bits(v0.x); out[1] = f2bf_bits(v0.y);
        out[2] = f2bf_bits(v0.z); out[3] = f2bf_bits(v0.w);
        out[4] = f2bf_bits(v1.x); out[5] = f2bf_bits(v1.y);
        out[6] = f2bf_bits(v1.z); out[7] = f2bf_bits(v1.w);
        *(uint4*)(xc + i) = *(const uint4*)out;
    } else {
        *(uint4*)(xc + i) = *(const uint4*)((const unsigned short*)src + o);
    }
}

// ---------------- W transpose+convert: wt[m][j*64+c] = bf16(W_m[c*64+j]) ----------------
__global__ __launch_bounds__(256) void transpose_w_kernel(
    const void* __restrict__ W0, const void* __restrict__ W1,
    const void* __restrict__ W2, const void* __restrict__ W3,
    const void* __restrict__ W4, const void* __restrict__ W5,
    const int* __restrict__ flagp, unsigned short* __restrict__ wt)
{
    const int f32 = *flagp;
    const void* src;
    switch (blockIdx.x) {
        case 0: src = W0; break; case 1: src = W1; break; case 2: src = W2; break;
        case 3: src = W3; break; case 4: src = W4; break; default: src = W5; break;
    }
    unsigned short* dst = wt + blockIdx.x * 4096;
    for (int i = threadIdx.x; i < 4096; i += 256) {
        int c = i >> 6, j = i & 63;
        dst[j * 64 + c] = f2bf_bits(ldf(src, c * 64 + j, f32));
    }
}

// ---------------- node prep (MFMA): one 16-node tile per wave; v stored bf16 ----------------
__global__ __launch_bounds__(256) void node_prep_mfma_kernel(
    const unsigned short* __restrict__ xc,
    const unsigned short* __restrict__ wt,
    const void* __restrict__ emb_a, const void* __restrict__ emb_b,
    const void* __restrict__ a_attn, const int* __restrict__ flagp,
    unsigned short* __restrict__ v_a, unsigned short* __restrict__ v_b,
    float* __restrict__ sq_a, float* __restrict__ sk_a,
    float* __restrict__ sq_b, float* __restrict__ sk_b,
    int n_nodes, int tiles)
{
    const int f32 = *flagp;
    const int wave_id = blockIdx.x * 4 + (threadIdx.x >> 6);
    if (wave_id >= 2 * tiles) return;
    const int type = (wave_id >= tiles);
    const int tile = type ? (wave_id - tiles) : wave_id;

    const unsigned short* xp = xc + (type ? (size_t)n_nodes * 64 : 0);
    const unsigned short* wq = wt + (type ? 3 * 4096 : 0);
    const unsigned short* wk = wq + 4096;
    const unsigned short* wv = wk + 4096;
    const void* embp = type ? emb_b : emb_a;
    unsigned short* v_out = type ? v_b : v_a;
    float2* sq_out = (float2*)(type ? sq_b : sq_a);
    float2* sk_out = (float2*)(type ? sk_b : sk_a);

    const int lane = threadIdx.x & 63;
    const int ml   = lane & 15;
    const int g    = lane >> 4;
    const int g8   = g * 8;

    float embc[4], acq[4], ack[4];
    #pragma unroll
    for (int t = 0; t < 4; ++t) {
        int colt = t * 16 + ml;
        embc[t] = ldf(embp, colt, f32);
        acq[t]  = ldf(a_attn, colt & 31, f32);
        ack[t]  = ldf(a_attn, 32 + (colt & 31), f32);
    }

    short8 Bq[4][2], Bk[4][2], Bv[4][2];
    #pragma unroll
    for (int t = 0; t < 4; ++t) {
        const int rowo = (t * 16 + ml) * 64;
        #pragma unroll
        for (int kh = 0; kh < 2; ++kh) {
            const int o = rowo + kh * 32 + g8;
            Bq[t][kh] = __builtin_bit_cast(short8, *(const uint4*)(wq + o));
            Bk[t][kh] = __builtin_bit_cast(short8, *(const uint4*)(wk + o));
            Bv[t][kh] = __builtin_bit_cast(short8, *(const uint4*)(wv + o));
        }
    }

    const int n0 = tile << 4;
    int nr = n0 + ml; if (nr > n_nodes - 1) nr = n_nodes - 1;
    const uint4* xr = (const uint4*)(xp + (size_t)nr * 64);
    short8 A0 = __builtin_bit_cast(short8, xr[g]);
    short8 A1 = __builtin_bit_cast(short8, xr[4 + g]);

    float4v accq[4], acck[4], accv[4];
    #pragma unroll
    for (int t = 0; t < 4; ++t) {
        float4v z = {0.f, 0.f, 0.f, 0.f};
        accq[t] = z; acck[t] = z; accv[t] = z;
    }
    #pragma unroll
    for (int t = 0; t < 4; ++t) {
        accq[t] = __builtin_amdgcn_mfma_f32_16x16x32_bf16(A0, Bq[t][0], accq[t], 0, 0, 0);
        accq[t] = __builtin_amdgcn_mfma_f32_16x16x32_bf16(A1, Bq[t][1], accq[t], 0, 0, 0);
        acck[t] = __builtin_amdgcn_mfma_f32_16x16x32_bf16(A0, Bk[t][0], acck[t], 0, 0, 0);
        acck[t] = __builtin_amdgcn_mfma_f32_16x16x32_bf16(A1, Bk[t][1], acck[t], 0, 0, 0);
        accv[t] = __builtin_amdgcn_mfma_f32_16x16x32_bf16(A0, Bv[t][0], accv[t], 0, 0, 0);
        accv[t] = __builtin_amdgcn_mfma_f32_16x16x32_bf16(A1, Bv[t][1], accv[t], 0, 0, 0);
    }

    // v store (bf16): D col = t*16+ml, node = n0 + g*4 + r
    #pragma unroll
    for (int t = 0; t < 4; ++t) {
        #pragma unroll
        for (int r = 0; r < 4; ++r) {
            int node = n0 + g * 4 + r;
            if (node < n_nodes)
                v_out[(size_t)node * 64 + t * 16 + ml] = f2bf_bits(accv[t][r]);
        }
    }

    #pragma unroll
    for (int r = 0; r < 4; ++r) {
        float q0 = fast_tanh(accq[0][r] + embc[0]) * acq[0]
                 + fast_tanh(accq[1][r] + embc[1]) * acq[1];
        float q1 = fast_tanh(accq[2][r] + embc[2]) * acq[2]
                 + fast_tanh(accq[3][r] + embc[3]) * acq[3];
        float k0 = fast_tanh(acck[0][r] + embc[0]) * ack[0]
                 + fast_tanh(acck[1][r] + embc[1]) * ack[1];
        float k1 = fast_tanh(acck[2][r] + embc[2]) * ack[2]
                 + fast_tanh(acck[3][r] + embc[3]) * ack[3];
        #pragma unroll
        for (int o = 1; o < 16; o <<= 1) {
            q0 += __shfl_xor(q0, o, 64); q1 += __shfl_xor(q1, o, 64);
            k0 += __shfl_xor(k0, o, 64); k1 += __shfl_xor(k1, o, 64);
        }
        int node = n0 + g * 4 + r;
        if (ml == 0 && node < n_nodes) {
            sq_out[node] = make_float2(q0, q1);
            sk_out[node] = make_float2(k0, k1);
        }
    }
}

// ---------------- relation constants ----------------
__global__ void rel_const_kernel(const void* __restrict__ rel1, const void* __restrict__ rel2,
                                 const void* __restrict__ a_attn, const int* __restrict__ flagp,
                                 float* __restrict__ cvals)
{
    const int f32 = *flagp;
    int t = threadIdx.x;
    const void* r = (t < 64) ? rel1 : rel2;
    int l = t & 63;
    float v = tanhf(ldf(r, l, f32)) * ldf(a_attn, 64 + (l & 31), f32);
    #pragma unroll
    for (int off = 16; off; off >>= 1) v += __shfl_xor(v, off, 32);
    if ((l & 31) == 0) cvals[(t >> 6) * 2 + (l >> 5)] = v;
}

// ---------------- precompute: M = blockdiag(We@Wo) [32x32], c32 = rel@Wo [32] ----------------
__global__ void precompute_kernel(const void* __restrict__ We, const void* __restrict__ Wo,
                                  const void* __restrict__ rel, const int* __restrict__ flagp,
                                  float* __restrict__ M, float* __restrict__ c32)
{
    const int f32 = *flagp;
    int t = threadIdx.x;            // 1024 threads
    int m = t >> 5, j = t & 31;
    int h = m >> 4, c = m & 15;
    float s = 0.f;
    for (int jj = 0; jj < 32; ++jj)
        s += ldf(We, c * 64 + h * 32 + jj, f32) * ldf(Wo, (size_t)(h * 32 + jj) * 32 + j, f32);
    M[m * 32 + j] = s;
    if (t < 32) {
        float s2 = 0.f;
        for (int ch = 0; ch < 64; ++ch)
            s2 += ldf(rel, ch, f32) * ldf(Wo, (size_t)ch * 32 + t, f32);
        c32[t] = s2;
    }
}

// ---------------- fused hist: both relations in one launch ----------------
__global__ __launch_bounds__(256) void hist_kernel(const int* __restrict__ col1,
                                                   const int* __restrict__ col2,
                                                   int* __restrict__ cnt, int N, int num_e)
{
    int e = blockIdx.x * 256 + threadIdx.x;
    if (e < num_e) atomicAdd(&cnt[col1[e]], 1);
    else if (e < 2 * num_e) atomicAdd(&cnt[N + col2[e - num_e]], 1);
}

__global__ __launch_bounds__(256) void scan1_kernel(const int* __restrict__ cnt,
                                                    int* __restrict__ partial, int n)
{
    __shared__ int wsum[4];
    int t = threadIdx.x;
    int i0 = blockIdx.x * 512 + 2 * t;
    int s = ((i0 < n) ? cnt[i0] : 0) + ((i0 + 1 < n) ? cnt[i0 + 1] : 0);
    #pragma unroll
    for (int o = 32; o; o >>= 1) s += __shfl_xor(s, o, 64);
    if ((t & 63) == 0) wsum[t >> 6] = s;
    __syncthreads();
    if (t == 0) partial[blockIdx.x] = wsum[0] + wsum[1] + wsum[2] + wsum[3];
}

__global__ void scan2_kernel(const int* __restrict__ partial, int* __restrict__ pp,
                             int* __restrict__ off, int nch, int noff)
{
    int lane = threadIdx.x;   // 64 threads
    int running = 0;
    for (int base = 0; base < nch; base += 64) {
        int i = base + lane;
        int o = (i < nch) ? partial[i] : 0;
        int v = o;
        #pragma unroll
        for (int d = 1; d < 64; d <<= 1) {
            int u = __shfl_up(v, d, 64);
            if (lane >= d) v += u;
        }
        if (i < nch) pp[i] = running + v - o;
        running += __shfl(v, 63, 64);
    }
    if (lane == 0) off[noff] = running;
}

__global__ __launch_bounds__(256) void scan3_kernel(const int* __restrict__ cnt,
                                                    const int* __restrict__ pp,
                                                    int* __restrict__ off,
                                                    int* __restrict__ cursor, int n)
{
    __shared__ int tmp[256];
    int t = threadIdx.x;
    int i0 = blockIdx.x * 512 + 2 * t;
    int v0 = (i0 < n) ? cnt[i0] : 0;
    int v1 = (i0 + 1 < n) ? cnt[i0 + 1] : 0;
    int pair = v0 + v1;
    tmp[t] = pair;
    __syncthreads();
    for (int d = 1; d < 256; d <<= 1) {
        int x = (t >= d) ? tmp[t - d] : 0;
        __syncthreads();
        tmp[t] += x;
        __syncthreads();
    }
    int excl = tmp[t] - pair + pp[blockIdx.x];
    if (i0 < n)     { off[i0] = excl;          cursor[i0] = excl; }
    if (i0 + 1 < n) { off[i0 + 1] = excl + v0; cursor[i0 + 1] = excl + v0; }
}

// ---------------- fused edge scores + scatter + denominator atomics ----------------
__global__ __launch_bounds__(256) void score_scatter_kernel(
    const void* __restrict__ ea, const void* __restrict__ We,
    const int* __restrict__ row, const int* __restrict__ col,
    const float* __restrict__ sq_dst, const float* __restrict__ sk_src,
    const float* __restrict__ cvals, const void* __restrict__ a_attn,
    const int* __restrict__ flagp,
    int* __restrict__ cursor, float* __restrict__ den,
    uint4* __restrict__ payload, int rb, int num_e)
{
    const int f32 = *flagp;
    __shared__ float We_s[16 * 64];
    __shared__ float a3_s[32];
    __shared__ float c_s[2];
    for (int i = threadIdx.x; i < 16 * 64; i += 256) We_s[i] = ldf(We, i, f32);
    if (threadIdx.x < 32) a3_s[threadIdx.x] = ldf(a_attn, 96 + threadIdx.x, f32);
    if (threadIdx.x < 2)  c_s[threadIdx.x]  = cvals[threadIdx.x];
    __syncthreads();

    const int e0 = blockIdx.x * 512 + threadIdx.x;
    const int e1 = e0 + 256;
    const bool v1 = (e1 < num_e);
    if (e0 >= num_e) return;

    float er0[16], er1[16];
    load_ea16(ea, (size_t)e0, f32, er0);
    if (v1) load_ea16(ea, (size_t)e1, f32, er1);
    else {
        #pragma unroll
        for (int c = 0; c < 16; ++c) er1[c] = 0.f;
    }

    float acc00 = 0.f, acc01 = 0.f, acc10 = 0.f, acc11 = 0.f;
    #pragma unroll 1                       // keep rolled: avoids VGPR blowup/spills
    for (int jb = 0; jb < 64; jb += 16) {
        float t0[16], t1[16];
        #pragma unroll
        for (int jj = 0; jj < 16; ++jj) { t0[jj] = 0.f; t1[jj] = 0.f; }
        #pragma unroll
        for (int c = 0; c < 16; ++c) {
            #pragma unroll
            for (int jj = 0; jj < 16; ++jj) {
                float w = We_s[c * 64 + jb + jj];
                t0[jj] += er0[c] * w;
                t1[jj] += er1[c] * w;
            }
        }
        float p0 = 0.f, p1 = 0.f;
        #pragma unroll
        for (int jj = 0; jj < 16; ++jj) {
            float a = a3_s[(jb + jj) & 31];
            p0 += fast_tanh(t0[jj]) * a;
            p1 += fast_tanh(t1[jj]) * a;
        }
        if (jb & 32) { acc01 += p0; acc11 += p1; }
        else         { acc00 += p0; acc10 += p1; }
    }

    {
        int d = col[e0], s = row[e0];
        float2 sqd = ((const float2*)sq_dst)[d];
        float2 sks = ((const float2*)sk_src)[s];
        float s0 = fminf(30.f, fmaxf(-30.f, acc00 + sqd.x + sks.x + c_s[0]));
        float s1 = fminf(30.f, fmaxf(-30.f, acc01 + sqd.y + sks.y + c_s[1]));
        float x0 = __expf(s0), x1 = __expf(s1);
        int pos = atomicAdd(&cursor[rb + d], 1);
        payload[pos] = make_uint4((unsigned)s, __float_as_uint(x0),
                                  __float_as_uint(x1), (unsigned)e0);
        atomicAdd(&den[(size_t)(rb + d) * 2 + 0], x0);
        atomicAdd(&den[(size_t)(rb + d) * 2 + 1], x1);
    }
    if (v1) {
        int d = col[e1], s = row[e1];
        float2 sqd = ((const float2*)sq_dst)[d];
        float2 sks = ((const float2*)sk_src)[s];
        float s0 = fminf(30.f, fmaxf(-30.f, acc10 + sqd.x + sks.x + c_s[0]));
        float s1 = fminf(30.f, fmaxf(-30.f, acc11 + sqd.y + sks.y + c_s[1]));
        float x0 = __expf(s0), x1 = __expf(s1);
        int pos = atomicAdd(&cursor[rb + d], 1);
        payload[pos] = make_uint4((unsigned)s, __float_as_uint(x0),
                                  __float_as_uint(x1), (unsigned)e1);
        atomicAdd(&den[(size_t)(rb + d) * 2 + 0], x0);
        atomicAdd(&den[(size_t)(rb + d) * 2 + 1], x1);
    }
}

// ---------------- reciprocal of denominators (in place) ----------------
__global__ __launch_bounds__(256) void recip_kernel(float* __restrict__ s, int n)
{
    int i = blockIdx.x * 256 + threadIdx.x;
    if (i < n) s[i] = __builtin_amdgcn_rcpf(s[i]);
}

// ---------------- fused aggregation + output projection (single pass, CSR) ----------------
__global__ __launch_bounds__(256) void agg_final_kernel(
    const uint4* __restrict__ payload, const int* __restrict__ off,
    const unsigned short* __restrict__ v_src, const unsigned short* __restrict__ xc,
    const void* __restrict__ ea, const void* __restrict__ Wo,
    const void* __restrict__ bo, const void* __restrict__ Wr,
    const float* __restrict__ M, const float* __restrict__ c32,
    const float* __restrict__ den_inv,
    const int* __restrict__ flagp, void* __restrict__ out,
    size_t out_elem_off, int relbase, int n_nodes)
{
    const int f32  = *flagp;
    const int lane = threadIdx.x & 63;
    const int wv   = threadIdx.x >> 6;
    const int j    = lane & 31;
    const int half = lane >> 5;

    __shared__ float stage[4][160];   // per-wave: y[64] | x[64] | u[32]

    float WoR[32], WrR[32], MR[16];
    const int cb = half * 32;
    #pragma unroll
    for (int cc = 0; cc < 32; ++cc) {
        WoR[cc] = ldf(Wo, (size_t)(cb + cc) * 32 + j, f32);
        WrR[cc] = ldf(Wr, (size_t)(cb + cc) * 32 + j, f32);
    }
    const int ub = half * 16;
    #pragma unroll
    for (int cc = 0; cc < 16; ++cc) MR[cc] = M[(ub + cc) * 32 + j];
    const float boR  = ldf(bo, j, f32);
    const float c32R = c32[j];

    const int stride = gridDim.x * 4;
    const int iters  = (n_nodes + stride - 1) / stride;
    int d = blockIdx.x * 4 + wv;

    for (int it = 0; it < iters; ++it, d += stride) {
        const bool valid = (d < n_nodes);
        const int dd  = valid ? d : (n_nodes - 1);
        const int idx = relbase + dd;
        const int b   = __builtin_amdgcn_readfirstlane(off[idx]);
        const int en  = __builtin_amdgcn_readfirstlane(off[idx + 1]);
        const int deg = en - b;

        float2 dinv = ((const float2*)den_inv)[idx];
        const float invh = (lane < 32) ? dinv.x : dinv.y;

        float y = 0.f, uacc = 0.f;
        const int c16 = lane & 15;
        #pragma unroll 4
        for (int k = b; k < en; ++k) {
            uint4 p = payload[k];
            float exh = (lane < 32) ? __uint_as_float(p.y) : __uint_as_float(p.z);
            float w = exh * invh;
            float vv = bf_bits2f(v_src[(size_t)p.x * 64 + lane]);
            y = fmaf(w, vv, y);
            float eav = ldf(ea, (size_t)p.w * 16 + c16, f32);
            uacc = fmaf(w, eav, uacc);
        }

        float xv = bf_bits2f(xc[(size_t)dd * 64 + lane]);

        float* st = stage[wv];
        st[lane] = y;
        st[64 + lane] = xv;
        if ((lane & 31) < 16) st[128 + half * 16 + c16] = uacc;
        __syncthreads();

        float acc = 0.f;
        #pragma unroll
        for (int cc = 0; cc < 32; ++cc) {
            acc = fmaf(st[cb + cc], WoR[cc], acc);
            acc = fmaf(st[64 + cb + cc], WrR[cc], acc);
        }
        #pragma unroll
        for (int cc = 0; cc < 16; ++cc)
            acc = fmaf(st[128 + ub + cc], MR[cc], acc);

        float other = __shfl(acc, lane ^ 32, 64);
        if (valid && lane < 32) {
            float o = acc + other + boR + ((deg > 0) ? c32R : 0.f);
            stf(out, out_elem_off + (size_t)dd * 32 + j, f32, o);
        }
        __syncthreads();
    }
}

extern "C" void kernel_launch(void* const* d_in, const int* in_sizes, int n_in,
                              void* d_out, int out_size, void* d_ws, size_t ws_size,
                              hipStream_t stream)
{
    const void* x_a   = d_in[0];
    const void* x_b   = d_in[1];
    const void* ea1   = d_in[2];
    const void* ea2   = d_in[3];
    const void* Wq_a  = d_in[4];
    const void* Wk_a  = d_in[5];
    const void* Wv_a  = d_in[6];
    const void* Wq_b  = d_in[7];
    const void* Wk_b  = d_in[8];
    const void* Wv_b  = d_in[9];
    const void* emb_a = d_in[10];
    const void* emb_b = d_in[11];
    const void* rel1  = d_in[12];
    const void* rel2  = d_in[13];
    const void* We    = d_in[14];
    const void* a_at  = d_in[15];
    const void* Wo_a  = d_in[16];
    const void* bo_a  = d_in[17];
    const void* Wo_b  = d_in[18];
    const void* bo_b  = d_in[19];
    const void* Wr_a  = d_in[20];
    const void* Wr_b  = d_in[21];
    const int*  row1  = (const int*)d_in[22];
    const int*  col1  = (const int*)d_in[23];
    const int*  row2  = (const int*)d_in[24];
    const int*  col2  = (const int*)d_in[25];

    const int N = in_sizes[0] / 64;   // nodes per type
    const int E = in_sizes[22];       // edges per relation

    // ---- workspace layout ----
    float* ws = (float*)d_ws;
    size_t off = 0;
    int*   flag = (int*)ws;        off += 64;
    unsigned short* v_a = (unsigned short*)(ws + off); off += (size_t)N * 32;  // bf16 v
    unsigned short* v_b = (unsigned short*)(ws + off); off += (size_t)N * 32;
    float* sq_a = ws + off;        off += (size_t)N * 2;
    float* sk_a = ws + off;        off += (size_t)N * 2;
    float* sq_b = ws + off;        off += (size_t)N * 2;
    float* sk_b = ws + off;        off += (size_t)N * 2;
    float* cvals = ws + off;       off += 4;
    off = (off + 3) & ~(size_t)3;
    unsigned short* wt = (unsigned short*)(ws + off); off += 6 * 4096 / 2;
    off = (off + 3) & ~(size_t)3;
    unsigned short* xc = (unsigned short*)(ws + off); off += (size_t)2 * N * 64 / 2;
    float* M1   = ws + off;        off += 1024;
    float* c321 = ws + off;        off += 32;
    float* M2   = ws + off;        off += 1024;
    float* c322 = ws + off;        off += 32;
    // zero region: cnt (2N ints) + den (4N floats), contiguous, single memset
    int*   cnt  = (int*)(ws + off);    off += (size_t)2 * N;
    float* den  = ws + off;            off += (size_t)4 * N;
    size_t zero_bytes = (size_t)(2 * N + 4 * N) * 4;
    int*   offs   = (int*)(ws + off);  off += (size_t)2 * N + 2;
    int*   cursor = (int*)(ws + off);  off += (size_t)2 * N;
    int*   partial = (int*)(ws + off); off += 512;
    int*   pp      = (int*)(ws + off); off += 512;
    off = (off + 3) & ~(size_t)3;
    uint4* payload = (uint4*)(ws + off); off += (size_t)2 * E * 4;

    const int tiles        = (N + 15) >> 4;
    const int mfma_blocks  = (2 * tiles + 3) / 4;
    const int conv_blocks  = (int)(((size_t)2 * N * 64 / 8 + 255) / 256);
    const int score_blocks = (E + 511) / 512;
    const int hist_blocks  = (2 * E + 255) / 256;
    const int nch          = (2 * N + 511) / 512;
    const int agg_blocks   = 2048;

    detect_kernel<<<1, 128, 0, stream>>>((const unsigned short*)a_at, flag);
    hipMemsetAsync(cnt, 0, zero_bytes, stream);

    convert_x_kernel<<<conv_blocks, 256, 0, stream>>>(x_a, x_b, flag, xc, (size_t)N * 64);
    transpose_w_kernel<<<6, 256, 0, stream>>>(Wq_a, Wk_a, Wv_a, Wq_b, Wk_b, Wv_b, flag, wt);
    node_prep_mfma_kernel<<<mfma_blocks, 256, 0, stream>>>(
        xc, wt, emb_a, emb_b, a_at, flag,
        v_a, v_b, sq_a, sk_a, sq_b, sk_b, N, tiles);

    rel_const_kernel<<<1, 128, 0, stream>>>(rel1, rel2, a_at, flag, cvals);
    precompute_kernel<<<1, 1024, 0, stream>>>(We, Wo_b, rel1, flag, M1, c321);  // rel1 -> out_b
    precompute_kernel<<<1, 1024, 0, stream>>>(We, Wo_a, rel2, flag, M2, c322);  // rel2 -> out_a

    hist_kernel<<<hist_blocks, 256, 0, stream>>>(col1, col2, cnt, N, E);
    scan1_kernel<<<nch, 256, 0, stream>>>(cnt, partial, 2 * N);
    scan2_kernel<<<1, 64, 0, stream>>>(partial, pp, offs, nch, 2 * N);
    scan3_kernel<<<nch, 256, 0, stream>>>(cnt, pp, offs, cursor, 2 * N);

    // fused score+scatter (+den atomics); rel1: a->b (dst base 0), rel2: b->a (dst base N)
    score_scatter_kernel<<<score_blocks, 256, 0, stream>>>(
        ea1, We, row1, col1, sq_b, sk_a, cvals + 0, a_at, flag, cursor, den, payload, 0, E);
    score_scatter_kernel<<<score_blocks, 256, 0, stream>>>(
        ea2, We, row2, col2, sq_a, sk_b, cvals + 2, a_at, flag, cursor, den, payload, N, E);

    recip_kernel<<<(4 * N + 255) / 256, 256, 0, stream>>>(den, 4 * N);

    agg_final_kernel<<<agg_blocks, 256, 0, stream>>>(payload, offs, v_a, xc + (size_t)N * 64,
                                                     ea1, Wo_b, bo_b, Wr_b, M1, c321, den,
                                                     flag, d_out, (size_t)N * 32, 0, N);
    agg_final_kernel<<<agg_blocks, 256, 0, stream>>>(payload, offs, v_b, xc,
                                                     ea2, Wo_a, bo_a, Wr_a, M2, c322, den,
                                                     flag, d_out, 0, N, N);
}